// Round 7
// baseline (486.003 us; speedup 1.0000x reference)
//
#include <hip/hip_runtime.h>
#include <hip/hip_bf16.h>
#include <stdint.h>

#define NB 2
#define SEQ 1024
#define DMODEL 768
#define NH 12
#define DH 64
#define SCALE 0.125f
#define NCH 4          // column chunks in fused attention

typedef __hip_bfloat16 bf16;
typedef __attribute__((ext_vector_type(8))) short short8;   // 8 x bf16 = 4 VGPRs
typedef __attribute__((ext_vector_type(4))) float f32x4;    // MFMA C/D

__device__ __forceinline__ float b2f(bf16 x){ return __bfloat162float(x); }
__device__ __forceinline__ bf16 f2b(float x){ return __float2bfloat16(x); }
__device__ __forceinline__ short f2bs(float x){
  bf16 h = __float2bfloat16(x); return *reinterpret_cast<short*>(&h);
}
__device__ __forceinline__ float s2f(short u){
  return __uint_as_float(((unsigned)(unsigned short)u) << 16);
}

// ---------------- f32 -> bf16 convert ----------------
__global__ __launch_bounds__(256) void cvt_kernel(const float* __restrict__ src,
                                                  bf16* __restrict__ dst, int n){
  int i = blockIdx.x*256 + threadIdx.x;
  if (i < n) dst[i] = f2b(src[i]);
}

// ---------------- LayerNorm: x[2048,768] f32 -> xn bf16 ----------------
__global__ __launch_bounds__(256) void ln_kernel(const float* __restrict__ x,
                                                 const float* __restrict__ g,
                                                 const float* __restrict__ bta,
                                                 bf16* __restrict__ xn){
  int row = blockIdx.x; int t = threadIdx.x;
  const float* xr = x + (size_t)row*DMODEL;
  float v0[3]; float s = 0.f, s2 = 0.f;
  #pragma unroll
  for (int i=0;i<3;i++){ float val = xr[t+256*i]; v0[i]=val; s+=val; s2+=val*val; }
  __shared__ float sb[256], s2b[256];
  sb[t]=s; s2b[t]=s2; __syncthreads();
  for (int off=128; off>0; off>>=1){
    if (t<off){ sb[t]+=sb[t+off]; s2b[t]+=s2b[t+off]; }
    __syncthreads();
  }
  float mean = sb[0]*(1.f/DMODEL);
  float var  = s2b[0]*(1.f/DMODEL) - mean*mean;
  float rstd = rsqrtf(var + 1e-5f);
  #pragma unroll
  for (int i=0;i<3;i++){
    int c = t+256*i;
    xn[(size_t)row*DMODEL + c] = f2b((v0[i]-mean)*rstd*g[c] + bta[c]);
  }
}

// ---------------- prep: block 0 computes M = (-0.5*theta)@gnn_w; blocks 1..96 zero l ----------------
__global__ __launch_bounds__(256) void prep_kernel(const float* __restrict__ theta,
                                                   const float* __restrict__ gnn,
                                                   float* __restrict__ Mm,
                                                   float* __restrict__ l){
  int bx = blockIdx.x, t = threadIdx.x;
  if (bx == 0){
    if (t < 144){
      int i = t/12, kx = t%12;
      float sacc = 0.f;
      for (int j=0;j<12;j++) sacc += (-0.5f)*theta[i*12+j] * gnn[j*12+kx];
      Mm[t] = sacc;
    }
  } else {
    l[(bx-1)*256 + t] = 0.f;      // 96*256 = 24576 = 2*12*1024
  }
}

// ---------------- QKV GEMM (MFMA): xn[2048,768] @ wqkv^T -> q,k bf16 [b,h,n,d]; v -> vt [b,h,d,n] ----------------
__global__ __launch_bounds__(256) void gemm_qkv(const bf16* __restrict__ A,
                                                const bf16* __restrict__ W,
                                                bf16* __restrict__ q,
                                                bf16* __restrict__ k,
                                                bf16* __restrict__ vt){
  __shared__ bf16 As[128*32];
  __shared__ bf16 Bs[128*32];
  int n0 = blockIdx.x*128, m0 = blockIdx.y*128;
  int t = threadIdx.x, w = t>>6, lane = t&63;
  int ln16 = lane&15, q8 = (lane>>4)*8;
  int wm = w>>1, wn = w&1;
  f32x4 acc[4][4] = {};
  for (int k0=0; k0<768; k0+=32){
    __syncthreads();
    #pragma unroll
    for (int i=0;i<2;i++){
      int cc = t + i*256;
      int r = cc>>2, ko = (cc&3)*8;
      *(short8*)&As[r*32+ko] = *(const short8*)&A[(size_t)(m0+r)*768 + k0+ko];
      *(short8*)&Bs[r*32+ko] = *(const short8*)&W[(size_t)(n0+r)*768 + k0+ko];
    }
    __syncthreads();
    short8 af[4], bfr[4];
    #pragma unroll
    for (int mi=0;mi<4;mi++) af[mi]  = *(const short8*)&As[(wm*64+mi*16+ln16)*32 + q8];
    #pragma unroll
    for (int ni=0;ni<4;ni++) bfr[ni] = *(const short8*)&Bs[(wn*64+ni*16+ln16)*32 + q8];
    #pragma unroll
    for (int mi=0;mi<4;mi++)
      #pragma unroll
      for (int ni=0;ni<4;ni++)
        acc[mi][ni] = __builtin_amdgcn_mfma_f32_16x16x32_bf16(af[mi], bfr[ni], acc[mi][ni], 0, 0, 0);
  }
  int quad4 = (lane>>4)*4;
  #pragma unroll
  for (int mi=0;mi<4;mi++){
    #pragma unroll
    for (int ni=0;ni<4;ni++){
      int cg = n0 + wn*64 + ni*16 + ln16;
      int which = cg/768; int rem = cg - which*768;
      int h = rem>>6, dd = rem&63;
      #pragma unroll
      for (int r=0;r<4;r++){
        int m = m0 + wm*64 + mi*16 + quad4 + r;
        int bb = m>>10, n = m&1023;
        float val = acc[mi][ni][r];
        if (which==0)      q [((size_t)(bb*NH+h)*SEQ + n)*DH + dd] = f2b(val*SCALE);
        else if (which==1) k [((size_t)(bb*NH+h)*SEQ + n)*DH + dd] = f2b(val);
        else               vt[((size_t)(bb*NH+h)*DH + dd)*SEQ + n] = f2b(val);
      }
    }
  }
}

// ---------------- pass 1 (col-chunked): l[b,h,n] += sum_chunk exp(s) ----------------
__global__ __launch_bounds__(768) void attn_sums(const bf16* __restrict__ q,
                                                 const bf16* __restrict__ k,
                                                 float* __restrict__ l){
  int b = blockIdx.z, ch = blockIdx.y; int r0 = blockIdx.x*16;
  int t = threadIdx.x; int h = t>>6; int lane = t&63;
  int ln16 = lane&15, quad = lane>>4; int q8 = quad*8, quad4 = quad*4;
  const bf16* qrow = q + ((size_t)(b*NH+h)*SEQ + r0 + ln16)*DH;
  short8 aq0 = *(const short8*)(qrow + q8);
  short8 aq1 = *(const short8*)(qrow + 32 + q8);
  const bf16* kB = k + ((size_t)(b*NH+h)*SEQ)*DH;
  float ls[4] = {0.f,0.f,0.f,0.f};
  for (int i=0;i<16;i++){
    int c0 = ch*256 + i*16;
    const bf16* krow = kB + (size_t)(c0 + ln16)*DH;
    short8 bk0 = *(const short8*)(krow + q8);
    short8 bk1 = *(const short8*)(krow + 32 + q8);
    f32x4 a = {0.f,0.f,0.f,0.f};
    a = __builtin_amdgcn_mfma_f32_16x16x32_bf16(aq0, bk0, a, 0, 0, 0);
    a = __builtin_amdgcn_mfma_f32_16x16x32_bf16(aq1, bk1, a, 0, 0, 0);
    #pragma unroll
    for (int r=0;r<4;r++) ls[r] += __expf(a[r]);
  }
  #pragma unroll
  for (int msk=1; msk<16; msk<<=1){
    #pragma unroll
    for (int r=0;r<4;r++) ls[r] += __shfl_xor(ls[r], msk);
  }
  if (ln16 == 0){
    #pragma unroll
    for (int r=0;r<4;r++)
      atomicAdd(&l[((size_t)(b*NH+h))*SEQ + r0 + quad4 + r], ls[r]);
  }
}

// ---------------- pass 2 (col-chunked): scores->softmax->mix(in-reg)->PV partial ----------------
// grid (64 strips, NCH chunks, NB), 768 threads = 12 waves, wave h = head h.
// attT[buf][head][row][col pad 40]: stride-1 cols -> conflict-free; dbl-buffered -> 1 barrier/tile.
__global__ __launch_bounds__(768, 6) void attn_main(const bf16* __restrict__ q,
                                                    const bf16* __restrict__ k,
                                                    const bf16* __restrict__ vt,
                                                    const float* __restrict__ Mm,
                                                    const float* __restrict__ l,
                                                    float* __restrict__ opart){
  __shared__ bf16 attT[2][NH][16][40];     // 2*12*16*40*2 = 30720 B
  int b = blockIdx.z, ch = blockIdx.y; int r0 = blockIdx.x*16;
  int t = threadIdx.x; int h = t>>6; int lane = t&63;
  int ln16 = lane&15, quad = lane>>4; int q8 = quad*8, quad4 = quad*4;
  const bf16* kB = k  + ((size_t)(b*NH+h)*SEQ)*DH;
  const bf16* vB = vt + ((size_t)(b*NH+h)*DH)*SEQ;

  // M row for this head (wave-uniform -> scalar regs)
  float Mrow[12];
  #pragma unroll
  for (int j=0;j<12;j++) Mrow[j] = Mm[h*12+j];

  // Q fragments for this head's 16 rows
  const bf16* qrow = q + ((size_t)(b*NH+h)*SEQ + r0 + ln16)*DH;
  short8 aq0 = *(const short8*)(qrow + q8);
  short8 aq1 = *(const short8*)(qrow + 32 + q8);

  // reciprocal denominators for this lane's 4 rows
  float inv_l[4];
  #pragma unroll
  for (int r=0;r<4;r++) inv_l[r] = 1.0f / l[((size_t)(b*NH+h))*SEQ + r0 + quad4 + r];

  f32x4 oacc[4] = {};
  for (int it=0; it<8; it++){
    int c0 = ch*256 + it*32;
    int buf = it&1;
    // phase A: normalized attn tile -> attT[buf][h][row][col]
    #pragma unroll
    for (int half=0; half<2; half++){
      const bf16* krow = kB + (size_t)(c0 + half*16 + ln16)*DH;
      short8 bk0 = *(const short8*)(krow + q8);
      short8 bk1 = *(const short8*)(krow + 32 + q8);
      f32x4 a = {0.f,0.f,0.f,0.f};
      a = __builtin_amdgcn_mfma_f32_16x16x32_bf16(aq0, bk0, a, 0, 0, 0);
      a = __builtin_amdgcn_mfma_f32_16x16x32_bf16(aq1, bk1, a, 0, 0, 0);
      #pragma unroll
      for (int r=0;r<4;r++)
        attT[buf][h][quad4+r][half*16 + ln16] = f2b(__expf(a[r])*inv_l[r]);
    }
    __syncthreads();
    // phase B: in-register head mix -> PV A-frag (comb[m=ln16][k=q8+e])
    float s0=0.f,s1=0.f,s2=0.f,s3=0.f,s4=0.f,s5=0.f,s6=0.f,s7=0.f;
    float a0=0.f,a1=0.f,a2=0.f,a3=0.f,a4=0.f,a5=0.f,a6=0.f,a7=0.f;
    #pragma unroll
    for (int j=0;j<12;j++){
      short8 u = *(const short8*)&attT[buf][j][ln16][q8];
      float m = Mrow[j];
      float v0=s2f(u[0]), v1=s2f(u[1]), v2=s2f(u[2]), v3=s2f(u[3]);
      float v4=s2f(u[4]), v5=s2f(u[5]), v6=s2f(u[6]), v7=s2f(u[7]);
      s0 += m*v0; s1 += m*v1; s2 += m*v2; s3 += m*v3;
      s4 += m*v4; s5 += m*v5; s6 += m*v6; s7 += m*v7;
      if (j == h){ a0=v0; a1=v1; a2=v2; a3=v3; a4=v4; a5=v5; a6=v6; a7=v7; }
    }
    short8 afrag;
    afrag[0]=f2bs(a0+fmaxf(s0,0.f)); afrag[1]=f2bs(a1+fmaxf(s1,0.f));
    afrag[2]=f2bs(a2+fmaxf(s2,0.f)); afrag[3]=f2bs(a3+fmaxf(s3,0.f));
    afrag[4]=f2bs(a4+fmaxf(s4,0.f)); afrag[5]=f2bs(a5+fmaxf(s5,0.f));
    afrag[6]=f2bs(a6+fmaxf(s6,0.f)); afrag[7]=f2bs(a7+fmaxf(s7,0.f));
    // phase C: O += comb @ V
    #pragma unroll
    for (int ni=0; ni<4; ni++){
      short8 bv = *(const short8*)&vB[(size_t)(ni*16 + ln16)*SEQ + c0 + q8];
      oacc[ni] = __builtin_amdgcn_mfma_f32_16x16x32_bf16(afrag, bv, oacc[ni], 0, 0, 0);
    }
  }
  // epilogue: partial O (f32) for this chunk
  float* dst = opart + ((size_t)ch*NB*SEQ + (size_t)b*SEQ)*DMODEL;
  #pragma unroll
  for (int ni=0; ni<4; ni++)
    #pragma unroll
    for (int r=0; r<4; r++){
      int n = r0 + quad4 + r;
      dst[(size_t)n*DMODEL + h*DH + ni*16 + ln16] = oacc[ni][r];
    }
}

// ---------------- reduce partials: aout = bf16( sum_ch opart ) ----------------
__global__ __launch_bounds__(256) void reduce_kernel(const float* __restrict__ opart,
                                                     bf16* __restrict__ aout){
  const size_t TOT = (size_t)NB*SEQ*DMODEL;      // 1,572,864
  size_t i = ((size_t)blockIdx.x*256 + threadIdx.x)*4;
  float4 s = *(const float4*)&opart[i];
  #pragma unroll
  for (int c=1;c<NCH;c++){
    float4 p = *(const float4*)&opart[c*TOT + i];
    s.x += p.x; s.y += p.y; s.z += p.z; s.w += p.w;
  }
  aout[i+0]=f2b(s.x); aout[i+1]=f2b(s.y); aout[i+2]=f2b(s.z); aout[i+3]=f2b(s.w);
}

// ---------------- out proj (MFMA): aout[2048,768] @ w_out^T + b_out -> f32 ----------------
__global__ __launch_bounds__(256) void gemm_out(const bf16* __restrict__ A,
                                                const bf16* __restrict__ W,
                                                const float* __restrict__ bias,
                                                float* __restrict__ out){
  __shared__ bf16 As[128*32];
  __shared__ bf16 Bs[128*32];
  int n0 = blockIdx.x*128, m0 = blockIdx.y*128;
  int t = threadIdx.x, w = t>>6, lane = t&63;
  int ln16 = lane&15, q8 = (lane>>4)*8;
  int wm = w>>1, wn = w&1;
  f32x4 acc[4][4] = {};
  for (int k0=0; k0<768; k0+=32){
    __syncthreads();
    #pragma unroll
    for (int i=0;i<2;i++){
      int cc = t + i*256;
      int r = cc>>2, ko = (cc&3)*8;
      *(short8*)&As[r*32+ko] = *(const short8*)&A[(size_t)(m0+r)*768 + k0+ko];
      *(short8*)&Bs[r*32+ko] = *(const short8*)&W[(size_t)(n0+r)*768 + k0+ko];
    }
    __syncthreads();
    short8 af[4], bfr[4];
    #pragma unroll
    for (int mi=0;mi<4;mi++) af[mi]  = *(const short8*)&As[(wm*64+mi*16+ln16)*32 + q8];
    #pragma unroll
    for (int ni=0;ni<4;ni++) bfr[ni] = *(const short8*)&Bs[(wn*64+ni*16+ln16)*32 + q8];
    #pragma unroll
    for (int mi=0;mi<4;mi++)
      #pragma unroll
      for (int ni=0;ni<4;ni++)
        acc[mi][ni] = __builtin_amdgcn_mfma_f32_16x16x32_bf16(af[mi], bfr[ni], acc[mi][ni], 0, 0, 0);
  }
  int quad4 = (lane>>4)*4;
  #pragma unroll
  for (int mi=0;mi<4;mi++)
    #pragma unroll
    for (int ni=0;ni<4;ni++){
      int cg = n0 + wn*64 + ni*16 + ln16;
      #pragma unroll
      for (int r=0;r<4;r++){
        int m = m0 + wm*64 + mi*16 + quad4 + r;
        out[(size_t)m*768 + cg] = acc[mi][ni][r] + bias[cg];
      }
    }
}

extern "C" void kernel_launch(void* const* d_in, const int* in_sizes, int n_in,
                              void* d_out, int out_size, void* d_ws, size_t ws_size,
                              hipStream_t stream){
  const float* x     = (const float*)d_in[0];
  const float* ln_g  = (const float*)d_in[1];
  const float* ln_b  = (const float*)d_in[2];
  const float* w_qkv = (const float*)d_in[3];
  const float* w_out = (const float*)d_in[4];
  const float* b_out = (const float*)d_in[5];
  const float* theta = (const float*)d_in[6];
  const float* gnn   = (const float*)d_in[7];
  float* out = (float*)d_out;

  char* p = (char*)d_ws;
  bf16* xnb   = (bf16*)p; p += (size_t)2048*768*2;
  bf16* wqkvb = (bf16*)p; p += (size_t)2304*768*2;
  bf16* woutb = (bf16*)p; p += (size_t)768*768*2;
  bf16* qb    = (bf16*)p; p += (size_t)NB*NH*SEQ*DH*2;
  bf16* kb    = (bf16*)p; p += (size_t)NB*NH*SEQ*DH*2;
  bf16* vtb   = (bf16*)p; p += (size_t)NB*NH*SEQ*DH*2;
  bf16* aoutb = (bf16*)p; p += (size_t)2048*768*2;
  float* Mm   = (float*)p; p += 256*4;
  float* lsum = (float*)p; p += (size_t)NB*NH*SEQ*4;
  float* opart= (float*)p;                        // NCH * 2048*768 f32 = 25.2 MB

  cvt_kernel<<<dim3((2304*768+255)/256), dim3(256), 0, stream>>>(w_qkv, wqkvb, 2304*768);
  cvt_kernel<<<dim3((768*768+255)/256),  dim3(256), 0, stream>>>(w_out, woutb, 768*768);
  ln_kernel<<<dim3(NB*SEQ), dim3(256), 0, stream>>>(x, ln_g, ln_b, xnb);
  prep_kernel<<<dim3(97), dim3(256), 0, stream>>>(theta, gnn, Mm, lsum);
  gemm_qkv<<<dim3(18, 16), dim3(256), 0, stream>>>(xnb, wqkvb, qb, kb, vtb);
  attn_sums<<<dim3(64, NCH, NB), dim3(768), 0, stream>>>(qb, kb, lsum);
  attn_main<<<dim3(64, NCH, NB), dim3(768), 0, stream>>>(qb, kb, vtb, Mm, lsum, opart);
  reduce_kernel<<<dim3((NB*SEQ*DMODEL/4+255)/256), dim3(256), 0, stream>>>(opart, aoutb);
  gemm_out<<<dim3(6, 16), dim3(256), 0, stream>>>(aoutb, woutb, b_out, out);
}

// Round 8
// 214.817 us; speedup vs baseline: 2.2624x; 2.2624x over previous
//
#include <hip/hip_runtime.h>
#include <hip/hip_bf16.h>
#include <stdint.h>

#define NB 2
#define SEQ 1024
#define DMODEL 768
#define NH 12
#define DH 64
#define SCALE 0.125f
#define NCH 4          // column chunks in fused attention

typedef __hip_bfloat16 bf16;
typedef __attribute__((ext_vector_type(8))) short short8;   // 8 x bf16 = 4 VGPRs
typedef __attribute__((ext_vector_type(4))) float f32x4;    // MFMA C/D

__device__ __forceinline__ float b2f(bf16 x){ return __bfloat162float(x); }
__device__ __forceinline__ bf16 f2b(float x){ return __float2bfloat16(x); }
__device__ __forceinline__ short f2bs(float x){
  bf16 h = __float2bfloat16(x); return *reinterpret_cast<short*>(&h);
}
__device__ __forceinline__ float s2f(short u){
  return __uint_as_float(((unsigned)(unsigned short)u) << 16);
}

// ---------------- f32 -> bf16 convert ----------------
__global__ __launch_bounds__(256) void cvt_kernel(const float* __restrict__ src,
                                                  bf16* __restrict__ dst, int n){
  int i = blockIdx.x*256 + threadIdx.x;
  if (i < n) dst[i] = f2b(src[i]);
}

// ---------------- LayerNorm: x[2048,768] f32 -> xn bf16 ----------------
__global__ __launch_bounds__(256) void ln_kernel(const float* __restrict__ x,
                                                 const float* __restrict__ g,
                                                 const float* __restrict__ bta,
                                                 bf16* __restrict__ xn){
  int row = blockIdx.x; int t = threadIdx.x;
  const float* xr = x + (size_t)row*DMODEL;
  float v0[3]; float s = 0.f, s2 = 0.f;
  #pragma unroll
  for (int i=0;i<3;i++){ float val = xr[t+256*i]; v0[i]=val; s+=val; s2+=val*val; }
  __shared__ float sb[256], s2b[256];
  sb[t]=s; s2b[t]=s2; __syncthreads();
  for (int off=128; off>0; off>>=1){
    if (t<off){ sb[t]+=sb[t+off]; s2b[t]+=s2b[t+off]; }
    __syncthreads();
  }
  float mean = sb[0]*(1.f/DMODEL);
  float var  = s2b[0]*(1.f/DMODEL) - mean*mean;
  float rstd = rsqrtf(var + 1e-5f);
  #pragma unroll
  for (int i=0;i<3;i++){
    int c = t+256*i;
    xn[(size_t)row*DMODEL + c] = f2b((v0[i]-mean)*rstd*g[c] + bta[c]);
  }
}

// ---------------- prep: block 0 computes M = (-0.5*theta)@gnn_w; blocks 1..96 zero l ----------------
__global__ __launch_bounds__(256) void prep_kernel(const float* __restrict__ theta,
                                                   const float* __restrict__ gnn,
                                                   float* __restrict__ Mm,
                                                   float* __restrict__ l){
  int bx = blockIdx.x, t = threadIdx.x;
  if (bx == 0){
    if (t < 144){
      int i = t/12, kx = t%12;
      float sacc = 0.f;
      for (int j=0;j<12;j++) sacc += (-0.5f)*theta[i*12+j] * gnn[j*12+kx];
      Mm[t] = sacc;
    }
  } else {
    l[(bx-1)*256 + t] = 0.f;      // 96*256 = 24576 = 2*12*1024
  }
}

// ---------------- QKV GEMM (MFMA): xn[2048,768] @ wqkv^T -> q,k bf16 [b,h,n,d]; v -> vt [b,h,d,n] ----------------
__global__ __launch_bounds__(256) void gemm_qkv(const bf16* __restrict__ A,
                                                const bf16* __restrict__ W,
                                                bf16* __restrict__ q,
                                                bf16* __restrict__ k,
                                                bf16* __restrict__ vt){
  __shared__ bf16 As[128*32];
  __shared__ bf16 Bs[128*32];
  int n0 = blockIdx.x*128, m0 = blockIdx.y*128;
  int t = threadIdx.x, w = t>>6, lane = t&63;
  int ln16 = lane&15, q8 = (lane>>4)*8;
  int wm = w>>1, wn = w&1;
  f32x4 acc[4][4] = {};
  for (int k0=0; k0<768; k0+=32){
    __syncthreads();
    #pragma unroll
    for (int i=0;i<2;i++){
      int cc = t + i*256;
      int r = cc>>2, ko = (cc&3)*8;
      *(short8*)&As[r*32+ko] = *(const short8*)&A[(size_t)(m0+r)*768 + k0+ko];
      *(short8*)&Bs[r*32+ko] = *(const short8*)&W[(size_t)(n0+r)*768 + k0+ko];
    }
    __syncthreads();
    short8 af[4], bfr[4];
    #pragma unroll
    for (int mi=0;mi<4;mi++) af[mi]  = *(const short8*)&As[(wm*64+mi*16+ln16)*32 + q8];
    #pragma unroll
    for (int ni=0;ni<4;ni++) bfr[ni] = *(const short8*)&Bs[(wn*64+ni*16+ln16)*32 + q8];
    #pragma unroll
    for (int mi=0;mi<4;mi++)
      #pragma unroll
      for (int ni=0;ni<4;ni++)
        acc[mi][ni] = __builtin_amdgcn_mfma_f32_16x16x32_bf16(af[mi], bfr[ni], acc[mi][ni], 0, 0, 0);
  }
  int quad4 = (lane>>4)*4;
  #pragma unroll
  for (int mi=0;mi<4;mi++){
    #pragma unroll
    for (int ni=0;ni<4;ni++){
      int cg = n0 + wn*64 + ni*16 + ln16;
      int which = cg/768; int rem = cg - which*768;
      int h = rem>>6, dd = rem&63;
      #pragma unroll
      for (int r=0;r<4;r++){
        int m = m0 + wm*64 + mi*16 + quad4 + r;
        int bb = m>>10, n = m&1023;
        float val = acc[mi][ni][r];
        if (which==0)      q [((size_t)(bb*NH+h)*SEQ + n)*DH + dd] = f2b(val*SCALE);
        else if (which==1) k [((size_t)(bb*NH+h)*SEQ + n)*DH + dd] = f2b(val);
        else               vt[((size_t)(bb*NH+h)*DH + dd)*SEQ + n] = f2b(val);
      }
    }
  }
}

// ---------------- pass 1 (col-chunked): l[b,h,n] += sum_chunk exp(s) ----------------
__global__ __launch_bounds__(768) void attn_sums(const bf16* __restrict__ q,
                                                 const bf16* __restrict__ k,
                                                 float* __restrict__ l){
  int b = blockIdx.z, ch = blockIdx.y; int r0 = blockIdx.x*16;
  int t = threadIdx.x; int h = t>>6; int lane = t&63;
  int ln16 = lane&15, quad = lane>>4; int q8 = quad*8, quad4 = quad*4;
  const bf16* qrow = q + ((size_t)(b*NH+h)*SEQ + r0 + ln16)*DH;
  short8 aq0 = *(const short8*)(qrow + q8);
  short8 aq1 = *(const short8*)(qrow + 32 + q8);
  const bf16* kB = k + ((size_t)(b*NH+h)*SEQ)*DH;
  float ls[4] = {0.f,0.f,0.f,0.f};
  for (int i=0;i<16;i++){
    int c0 = ch*256 + i*16;
    const bf16* krow = kB + (size_t)(c0 + ln16)*DH;
    short8 bk0 = *(const short8*)(krow + q8);
    short8 bk1 = *(const short8*)(krow + 32 + q8);
    f32x4 a = {0.f,0.f,0.f,0.f};
    a = __builtin_amdgcn_mfma_f32_16x16x32_bf16(aq0, bk0, a, 0, 0, 0);
    a = __builtin_amdgcn_mfma_f32_16x16x32_bf16(aq1, bk1, a, 0, 0, 0);
    #pragma unroll
    for (int r=0;r<4;r++) ls[r] += __expf(a[r]);
  }
  #pragma unroll
  for (int msk=1; msk<16; msk<<=1){
    #pragma unroll
    for (int r=0;r<4;r++) ls[r] += __shfl_xor(ls[r], msk);
  }
  if (ln16 == 0){
    #pragma unroll
    for (int r=0;r<4;r++)
      atomicAdd(&l[((size_t)(b*NH+h))*SEQ + r0 + quad4 + r], ls[r]);
  }
}

// ---------------- pass 2 (col-chunked): scores->softmax->mix(in-reg)->PV partial ----------------
// grid (64 strips, NCH chunks, NB), 768 threads = 12 waves, wave h = head h.
// attT[buf][head][row][col pad 40]: stride-1 cols -> conflict-free; dbl-buffered -> 1 barrier/tile.
// NOTE: no min-waves launch bound — round 7's (768,6) forced scratch spills (897 MB WRITE_SIZE).
__global__ __launch_bounds__(768) void attn_main(const bf16* __restrict__ q,
                                                 const bf16* __restrict__ k,
                                                 const bf16* __restrict__ vt,
                                                 const float* __restrict__ Mm,
                                                 const float* __restrict__ l,
                                                 float* __restrict__ opart){
  __shared__ bf16 attT[2][NH][16][40];     // 2*12*16*40*2 = 30720 B
  __shared__ float Ms[144];
  int b = blockIdx.z, ch = blockIdx.y; int r0 = blockIdx.x*16;
  int t = threadIdx.x; int h = t>>6; int lane = t&63;
  int ln16 = lane&15, quad = lane>>4; int q8 = quad*8, quad4 = quad*4;
  const bf16* kB = k  + ((size_t)(b*NH+h)*SEQ)*DH;
  const bf16* vB = vt + ((size_t)(b*NH+h)*DH)*SEQ;

  if (t < 144) Ms[t] = Mm[t];              // covered by iteration-0 barrier

  // Q fragments for this head's 16 rows
  const bf16* qrow = q + ((size_t)(b*NH+h)*SEQ + r0 + ln16)*DH;
  short8 aq0 = *(const short8*)(qrow + q8);
  short8 aq1 = *(const short8*)(qrow + 32 + q8);

  // reciprocal denominators for this lane's 4 rows
  float inv_l[4];
  #pragma unroll
  for (int r=0;r<4;r++) inv_l[r] = 1.0f / l[((size_t)(b*NH+h))*SEQ + r0 + quad4 + r];

  f32x4 oacc[4] = {};
  for (int it=0; it<8; it++){
    int c0 = ch*256 + it*32;
    int buf = it&1;
    // phase A: normalized attn tile -> attT[buf][h][row][col]
    #pragma unroll
    for (int half=0; half<2; half++){
      const bf16* krow = kB + (size_t)(c0 + half*16 + ln16)*DH;
      short8 bk0 = *(const short8*)(krow + q8);
      short8 bk1 = *(const short8*)(krow + 32 + q8);
      f32x4 a = {0.f,0.f,0.f,0.f};
      a = __builtin_amdgcn_mfma_f32_16x16x32_bf16(aq0, bk0, a, 0, 0, 0);
      a = __builtin_amdgcn_mfma_f32_16x16x32_bf16(aq1, bk1, a, 0, 0, 0);
      #pragma unroll
      for (int r=0;r<4;r++)
        attT[buf][h][quad4+r][half*16 + ln16] = f2b(__expf(a[r])*inv_l[r]);
    }
    __syncthreads();
    // phase B: in-register head mix -> PV A-frag (comb[m=ln16][k=q8+e])
    float sm[8] = {0.f,0.f,0.f,0.f,0.f,0.f,0.f,0.f};
    #pragma unroll
    for (int j=0;j<12;j++){
      short8 u = *(const short8*)&attT[buf][j][ln16][q8];
      float m = Ms[h*12+j];
      #pragma unroll
      for (int e=0;e<8;e++) sm[e] += m*s2f(u[e]);
    }
    short8 uh = *(const short8*)&attT[buf][h][ln16][q8];
    short8 afrag;
    #pragma unroll
    for (int e=0;e<8;e++) afrag[e] = f2bs(s2f(uh[e]) + fmaxf(sm[e], 0.f));
    // phase C: O += comb @ V
    #pragma unroll
    for (int ni=0; ni<4; ni++){
      short8 bv = *(const short8*)&vB[(size_t)(ni*16 + ln16)*SEQ + c0 + q8];
      oacc[ni] = __builtin_amdgcn_mfma_f32_16x16x32_bf16(afrag, bv, oacc[ni], 0, 0, 0);
    }
  }
  // epilogue: partial O (f32) for this chunk
  float* dst = opart + ((size_t)ch*NB*SEQ + (size_t)b*SEQ)*DMODEL;
  #pragma unroll
  for (int ni=0; ni<4; ni++)
    #pragma unroll
    for (int r=0; r<4; r++){
      int n = r0 + quad4 + r;
      dst[(size_t)n*DMODEL + h*DH + ni*16 + ln16] = oacc[ni][r];
    }
}

// ---------------- reduce partials: aout = bf16( sum_ch opart ) ----------------
__global__ __launch_bounds__(256) void reduce_kernel(const float* __restrict__ opart,
                                                     bf16* __restrict__ aout){
  const size_t TOT = (size_t)NB*SEQ*DMODEL;      // 1,572,864
  size_t i = ((size_t)blockIdx.x*256 + threadIdx.x)*4;
  float4 s = *(const float4*)&opart[i];
  #pragma unroll
  for (int c=1;c<NCH;c++){
    float4 p = *(const float4*)&opart[c*TOT + i];
    s.x += p.x; s.y += p.y; s.z += p.z; s.w += p.w;
  }
  aout[i+0]=f2b(s.x); aout[i+1]=f2b(s.y); aout[i+2]=f2b(s.z); aout[i+3]=f2b(s.w);
}

// ---------------- out proj (MFMA): aout[2048,768] @ w_out^T + b_out -> f32 ----------------
__global__ __launch_bounds__(256) void gemm_out(const bf16* __restrict__ A,
                                                const bf16* __restrict__ W,
                                                const float* __restrict__ bias,
                                                float* __restrict__ out){
  __shared__ bf16 As[128*32];
  __shared__ bf16 Bs[128*32];
  int n0 = blockIdx.x*128, m0 = blockIdx.y*128;
  int t = threadIdx.x, w = t>>6, lane = t&63;
  int ln16 = lane&15, q8 = (lane>>4)*8;
  int wm = w>>1, wn = w&1;
  f32x4 acc[4][4] = {};
  for (int k0=0; k0<768; k0+=32){
    __syncthreads();
    #pragma unroll
    for (int i=0;i<2;i++){
      int cc = t + i*256;
      int r = cc>>2, ko = (cc&3)*8;
      *(short8*)&As[r*32+ko] = *(const short8*)&A[(size_t)(m0+r)*768 + k0+ko];
      *(short8*)&Bs[r*32+ko] = *(const short8*)&W[(size_t)(n0+r)*768 + k0+ko];
    }
    __syncthreads();
    short8 af[4], bfr[4];
    #pragma unroll
    for (int mi=0;mi<4;mi++) af[mi]  = *(const short8*)&As[(wm*64+mi*16+ln16)*32 + q8];
    #pragma unroll
    for (int ni=0;ni<4;ni++) bfr[ni] = *(const short8*)&Bs[(wn*64+ni*16+ln16)*32 + q8];
    #pragma unroll
    for (int mi=0;mi<4;mi++)
      #pragma unroll
      for (int ni=0;ni<4;ni++)
        acc[mi][ni] = __builtin_amdgcn_mfma_f32_16x16x32_bf16(af[mi], bfr[ni], acc[mi][ni], 0, 0, 0);
  }
  int quad4 = (lane>>4)*4;
  #pragma unroll
  for (int mi=0;mi<4;mi++)
    #pragma unroll
    for (int ni=0;ni<4;ni++){
      int cg = n0 + wn*64 + ni*16 + ln16;
      #pragma unroll
      for (int r=0;r<4;r++){
        int m = m0 + wm*64 + mi*16 + quad4 + r;
        out[(size_t)m*768 + cg] = acc[mi][ni][r] + bias[cg];
      }
    }
}

extern "C" void kernel_launch(void* const* d_in, const int* in_sizes, int n_in,
                              void* d_out, int out_size, void* d_ws, size_t ws_size,
                              hipStream_t stream){
  const float* x     = (const float*)d_in[0];
  const float* ln_g  = (const float*)d_in[1];
  const float* ln_b  = (const float*)d_in[2];
  const float* w_qkv = (const float*)d_in[3];
  const float* w_out = (const float*)d_in[4];
  const float* b_out = (const float*)d_in[5];
  const float* theta = (const float*)d_in[6];
  const float* gnn   = (const float*)d_in[7];
  float* out = (float*)d_out;

  char* p = (char*)d_ws;
  bf16* xnb   = (bf16*)p; p += (size_t)2048*768*2;
  bf16* wqkvb = (bf16*)p; p += (size_t)2304*768*2;
  bf16* woutb = (bf16*)p; p += (size_t)768*768*2;
  bf16* qb    = (bf16*)p; p += (size_t)NB*NH*SEQ*DH*2;
  bf16* kb    = (bf16*)p; p += (size_t)NB*NH*SEQ*DH*2;
  bf16* vtb   = (bf16*)p; p += (size_t)NB*NH*SEQ*DH*2;
  bf16* aoutb = (bf16*)p; p += (size_t)2048*768*2;
  float* Mm   = (float*)p; p += 256*4;
  float* lsum = (float*)p; p += (size_t)NB*NH*SEQ*4;
  float* opart= (float*)p;                        // NCH * 2048*768 f32 = 25.2 MB

  cvt_kernel<<<dim3((2304*768+255)/256), dim3(256), 0, stream>>>(w_qkv, wqkvb, 2304*768);
  cvt_kernel<<<dim3((768*768+255)/256),  dim3(256), 0, stream>>>(w_out, woutb, 768*768);
  ln_kernel<<<dim3(NB*SEQ), dim3(256), 0, stream>>>(x, ln_g, ln_b, xnb);
  prep_kernel<<<dim3(97), dim3(256), 0, stream>>>(theta, gnn, Mm, lsum);
  gemm_qkv<<<dim3(18, 16), dim3(256), 0, stream>>>(xnb, wqkvb, qb, kb, vtb);
  attn_sums<<<dim3(64, NCH, NB), dim3(768), 0, stream>>>(qb, kb, lsum);
  attn_main<<<dim3(64, NCH, NB), dim3(768), 0, stream>>>(qb, kb, vtb, Mm, lsum, opart);
  reduce_kernel<<<dim3((NB*SEQ*DMODEL/4+255)/256), dim3(256), 0, stream>>>(opart, aoutb);
  gemm_out<<<dim3(6, 16), dim3(256), 0, stream>>>(aoutb, woutb, b_out, out);
}